// Round 1
// baseline (105.453 us; speedup 1.0000x reference)
//
#include <hip/hip_runtime.h>
#include <math.h>

#define B_ 4
#define C_ 64
#define D_ 32
#define H_ 64
#define W_ 64
#define S_ (D_*H_*W_)      // 131072 spatial per (b,c)
#define S4_ (S_/4)         // 32768

// ---------------- Kernel 1: channel-wise max & mean -> xc[B][2][D][H][W] ----
__global__ __launch_bounds__(256) void reduce_kernel(const float* __restrict__ x,
                                                     float* __restrict__ xc) {
    int i  = blockIdx.x * 256 + threadIdx.x;          // float4 index over B*S/4
    int b  = i >> 15;                                  // i / S4_ (S4_=32768, B*S4_=131072)
    int s4 = i & (S4_ - 1);
    const float4* x4 = reinterpret_cast<const float4*>(x) + (size_t)b * C_ * S4_ + s4;
    float4 v = x4[0];
    float mx0 = v.x, mx1 = v.y, mx2 = v.z, mx3 = v.w;
    float sm0 = v.x, sm1 = v.y, sm2 = v.z, sm3 = v.w;
    #pragma unroll 8
    for (int c = 1; c < C_; ++c) {
        float4 t = x4[(size_t)c * S4_];
        mx0 = fmaxf(mx0, t.x); sm0 += t.x;
        mx1 = fmaxf(mx1, t.y); sm1 += t.y;
        mx2 = fmaxf(mx2, t.z); sm2 += t.z;
        mx3 = fmaxf(mx3, t.w); sm3 += t.w;
    }
    float4* o = reinterpret_cast<float4*>(xc);
    float4 a; a.x = mx0; a.y = mx1; a.z = mx2; a.w = mx3;
    o[((size_t)b * 2 + 0) * S4_ + s4] = a;
    const float inv = 1.0f / 64.0f;
    float4 m; m.x = sm0 * inv; m.y = sm1 * inv; m.z = sm2 * inv; m.w = sm3 * inv;
    o[((size_t)b * 2 + 1) * S4_ + s4] = m;
}

// ---------------- Kernel 2: conv3d(2->1, k7, pad3) + sigmoid -> scale -------
// Tile: 16(W) x 8(H) x 8(D) outputs per 256-thread block, 4 W-outputs/thread.
// LDS halo: 2 x 14 x 14 x 22 (stored with row stride 24 for 16B alignment).
#define RX 24              // padded row stride (floats)
#define RYS (14*RX)        // 336: z stride
#define CHS (14*RYS)       // 4704: channel stride
__global__ __launch_bounds__(256) void conv_kernel(const float* __restrict__ xc,
                                                   const float* __restrict__ cw,
                                                   const float* __restrict__ cb,
                                                   float* __restrict__ scale) {
    __shared__ float tile[2 * CHS];     // 9408 floats
    __shared__ float wl[2 * 392];       // weights padded to 8 per kw-row

    const int tid = threadIdx.x;
    const int b  = blockIdx.z >> 2;
    const int d0 = (blockIdx.z & 3) * 8;
    const int h0 = blockIdx.y * 8;
    const int w0 = blockIdx.x * 16;

    // halo load (logical extent 2 x 14 x 14 x 22)
    for (int idx = tid; idx < 2 * 14 * 14 * 22; idx += 256) {
        int ch = idx / (14 * 14 * 22);
        int r  = idx - ch * (14 * 14 * 22);
        int z  = r / (14 * 22);
        r     -= z * (14 * 22);
        int y  = r / 22;
        int xw = r - y * 22;
        int gd = d0 + z - 3, gh = h0 + y - 3, gw = w0 + xw - 3;
        float v = 0.0f;
        if ((unsigned)gd < (unsigned)D_ && (unsigned)gh < (unsigned)H_ &&
            (unsigned)gw < (unsigned)W_)
            v = xc[((size_t)(b * 2 + ch)) * S_ + gd * (H_ * W_) + gh * W_ + gw];
        tile[ch * CHS + z * RYS + y * RX + xw] = v;
    }
    // weights: wl[ch][kz][ky][8] (8th lane zero-padded)
    for (int idx = tid; idx < 784; idx += 256) {
        int ch = idx / 392;
        int r  = idx - ch * 392;
        int kz = r / 56;
        int r2 = r - kz * 56;
        int ky = r2 >> 3;
        int kw = r2 & 7;
        wl[idx] = (kw < 7) ? cw[ch * 343 + kz * 49 + ky * 7 + kw] : 0.0f;
    }
    __syncthreads();

    const int txg = tid & 3;          // 4 outputs along W each
    const int ty  = (tid >> 2) & 7;
    const int tz  = tid >> 5;

    float acc0 = 0.f, acc1 = 0.f, acc2 = 0.f, acc3 = 0.f;
    for (int ch = 0; ch < 2; ++ch) {
        for (int kz = 0; kz < 7; ++kz) {
            #pragma unroll
            for (int ky = 0; ky < 7; ++ky) {
                const float* row = &tile[ch * CHS + (tz + kz) * RYS + (ty + ky) * RX + txg * 4];
                float4 f0 = *reinterpret_cast<const float4*>(row);
                float4 f1 = *reinterpret_cast<const float4*>(row + 4);
                float2 f2 = *reinterpret_cast<const float2*>(row + 8);
                float win[10] = {f0.x, f0.y, f0.z, f0.w, f1.x, f1.y, f1.z, f1.w, f2.x, f2.y};
                const float* wr = &wl[ch * 392 + kz * 56 + ky * 8];
                float4 wa = *reinterpret_cast<const float4*>(wr);
                float4 wb = *reinterpret_cast<const float4*>(wr + 4);
                float wt[7] = {wa.x, wa.y, wa.z, wa.w, wb.x, wb.y, wb.z};
                #pragma unroll
                for (int kw = 0; kw < 7; ++kw) {
                    acc0 = fmaf(win[kw + 0], wt[kw], acc0);
                    acc1 = fmaf(win[kw + 1], wt[kw], acc1);
                    acc2 = fmaf(win[kw + 2], wt[kw], acc2);
                    acc3 = fmaf(win[kw + 3], wt[kw], acc3);
                }
            }
        }
    }
    const float bias = cb[0];
    float4 sv;
    sv.x = 1.0f / (1.0f + __expf(-(acc0 + bias)));
    sv.y = 1.0f / (1.0f + __expf(-(acc1 + bias)));
    sv.z = 1.0f / (1.0f + __expf(-(acc2 + bias)));
    sv.w = 1.0f / (1.0f + __expf(-(acc3 + bias)));
    const int d = d0 + tz, h = h0 + ty, w = w0 + txg * 4;
    *reinterpret_cast<float4*>(&scale[(size_t)b * S_ + d * (H_ * W_) + h * W_ + w]) = sv;
}

// ---------------- Kernel 3: out = x * scale (broadcast over C) --------------
__global__ __launch_bounds__(256) void scale_kernel(const float* __restrict__ x,
                                                    const float* __restrict__ scale,
                                                    float* __restrict__ out) {
    size_t i = (size_t)blockIdx.x * 256 + threadIdx.x;   // float4 index
    int b   = (int)(i >> 21);                             // / (C_*S4_) = 2097152
    int s4  = (int)(i & (S4_ - 1));
    float4 xv = reinterpret_cast<const float4*>(x)[i];
    float4 sv = reinterpret_cast<const float4*>(scale)[(size_t)b * S4_ + s4];
    float4 o;
    o.x = xv.x * sv.x; o.y = xv.y * sv.y; o.z = xv.z * sv.z; o.w = xv.w * sv.w;
    reinterpret_cast<float4*>(out)[i] = o;
}

extern "C" void kernel_launch(void* const* d_in, const int* in_sizes, int n_in,
                              void* d_out, int out_size, void* d_ws, size_t ws_size,
                              hipStream_t stream) {
    const float* x  = (const float*)d_in[0];
    const float* cw = (const float*)d_in[1];   // [1][2][7][7][7]
    const float* cb = (const float*)d_in[2];   // [1]
    float* out   = (float*)d_out;
    float* xc    = (float*)d_ws;                       // B*2*S floats (4 MiB)
    float* scale = xc + (size_t)B_ * 2 * S_;           // B*S floats (2 MiB)

    reduce_kernel<<<dim3((B_ * S4_) / 256), dim3(256), 0, stream>>>(x, xc);
    conv_kernel<<<dim3(W_ / 16, H_ / 8, B_ * D_ / 8), dim3(256), 0, stream>>>(xc, cw, cb, scale);
    scale_kernel<<<dim3((size_t)B_ * C_ * S4_ / 256), dim3(256), 0, stream>>>(x, scale, out);
}